// Round 1
// baseline (894.523 us; speedup 1.0000x reference)
//
#include <hip/hip_runtime.h>
#include <math.h>
#include <stdint.h>

#define DEV static __device__ __forceinline__

typedef __bf16 bf16x8 __attribute__((ext_vector_type(8)));
typedef __bf16 bf16x4v __attribute__((ext_vector_type(4)));
typedef float f32x4 __attribute__((ext_vector_type(4)));

// problem dims
constexpr int Bb = 2, Nn = 2048, Ll = 2048, Ee = 1024, Hh = 16;
constexpr float SCALE = 0.0625f;   // (4C)^-0.5 = 1/16

// ---------------- workspace layout (bytes) ----------------
constexpr size_t OFF_XN  = 0;                         // [4096][1024] bf16
constexpr size_t OFF_YNK = OFF_XN  + 8388608;
constexpr size_t OFF_YNV = OFF_YNK + 8388608;
constexpr size_t OFF_H   = OFF_YNV + 8388608;         // [4096][2048] bf16 (reused 3x)
constexpr size_t OFF_X1  = OFF_H   + 16777216;
constexpr size_t OFF_X2  = OFF_X1  + 8388608;
constexpr size_t OFF_Y1  = OFF_X2  + 8388608;
constexpr size_t OFF_QWS = OFF_Y1  + 8388608;         // [B][H][N][256] bf16, pre-swizzled
constexpr size_t OFF_KWS = OFF_QWS + 33554432;        // [B][H][L][256] bf16, pre-swizzled
constexpr size_t OFF_VWS = OFF_KWS + 33554432;        // [B][H][L][64] bf16
constexpr size_t OFF_SM  = OFF_VWS + 8388608;         // f32 [B*H*N]
constexpr size_t OFF_SS  = OFF_SM  + 262144;
constexpr size_t OFF_ST  = OFF_SS  + 262144;
constexpr size_t OFF_AVZ = OFF_ST  + 262144;          // [4096][1088] bf16 : [attn_v | z]
constexpr size_t OFF_W11 = OFF_AVZ + 8912896;         // bf16 weights
constexpr size_t OFF_W12 = OFF_W11 + 4194304;
constexpr size_t OFF_W21 = OFF_W12 + 4194304;
constexpr size_t OFF_W22 = OFF_W21 + 4194304;
constexpr size_t OFF_WK1 = OFF_W22 + 4194304;
constexpr size_t OFF_WK2 = OFF_WK1 + 4194304;
constexpr size_t OFF_WV  = OFF_WK2 + 4194304;
constexpr size_t OFF_WP  = OFF_WV  + 2097152;         // [1024][1088] bf16 fused proj

DEV void gl2l(const void* g, void* l) {
  __builtin_amdgcn_global_load_lds((const __attribute__((address_space(1))) void*)g,
                                   (__attribute__((address_space(3))) void*)l, 16, 0, 0);
}

// ---------------- dtype conversion ----------------
__launch_bounds__(256)
__global__ void cvt_bf16(const float* __restrict__ s, __bf16* __restrict__ d, int n4) {
  int i = blockIdx.x * 256 + threadIdx.x;
  if (i < n4) {
    float4 v = ((const float4*)s)[i];
    bf16x4v o; o[0]=(__bf16)v.x; o[1]=(__bf16)v.y; o[2]=(__bf16)v.z; o[3]=(__bf16)v.w;
    ((bf16x4v*)d)[i] = o;
  }
}

__launch_bounds__(256)
__global__ void cvt_proj(const float* __restrict__ w1, const float* __restrict__ w2,
                         __bf16* __restrict__ d) {
  for (size_t i = blockIdx.x * 256ul + threadIdx.x; i < 1024ul * 1088ul; i += 262144ul) {
    size_t row = i / 1088, col = i - row * 1088;
    float v = (col < 1024) ? w1[row * 1024 + col] : w2[(row << 6) + (col - 1024)];
    d[i] = (__bf16)v;
  }
}

// ---------------- LayerNorm (one block per token) ----------------
__launch_bounds__(256)
__global__ void ln_kernel(const float* __restrict__ x, const float* __restrict__ gam,
                          const float* __restrict__ bet, __bf16* __restrict__ out) {
  const int t = blockIdx.x, tid = threadIdx.x;
  const float4 v = ((const float4*)(x + (size_t)t * Ee))[tid];
  float s = v.x + v.y + v.z + v.w;
  float q = v.x*v.x + v.y*v.y + v.z*v.z + v.w*v.w;
  #pragma unroll
  for (int o = 32; o > 0; o >>= 1) { s += __shfl_down(s, o); q += __shfl_down(q, o); }
  __shared__ float ls[4], lq[4];
  if ((tid & 63) == 0) { ls[tid >> 6] = s; lq[tid >> 6] = q; }
  __syncthreads();
  s = ls[0] + ls[1] + ls[2] + ls[3];
  q = lq[0] + lq[1] + lq[2] + lq[3];
  const float mu = s * (1.f / Ee);
  const float rstd = rsqrtf(q * (1.f / Ee) - mu * mu + 1e-5f);
  const int e0 = tid << 2;
  bf16x4v o;
  o[0] = (__bf16)((v.x - mu) * rstd * gam[e0]   + bet[e0]);
  o[1] = (__bf16)((v.y - mu) * rstd * gam[e0+1] + bet[e0+1]);
  o[2] = (__bf16)((v.z - mu) * rstd * gam[e0+2] + bet[e0+2]);
  o[3] = (__bf16)((v.w - mu) * rstd * gam[e0+3] + bet[e0+3]);
  *(bf16x4v*)(out + (size_t)t * Ee + e0) = o;
}

// ---------------- NT GEMM: C[m,n] = sum_k A[m,k] * W[n,k] (+bias) ----------------
// 128x128 tile, BK=32, 4 waves (2x2), 16x16x32 bf16 MFMA, global_load_lds w=16,
// chunk-XOR swizzle (row&3) on the 4 16B-chunks/row.
// MODE: 0 = bf16 out + bias; 1 = + GELU(exact); 2 = bf16 vhead layout; 3 = f32 out + bias1+bias2
template<int MODE>
__launch_bounds__(256)
__global__ void gemm_nt(const __bf16* __restrict__ A, int lda,
                        const __bf16* __restrict__ W, int ldw,
                        const float* __restrict__ bias1, const float* __restrict__ bias2,
                        void* __restrict__ out, int M, int N, int K) {
  __shared__ __align__(16) __bf16 As[128 * 32];
  __shared__ __align__(16) __bf16 Bs[128 * 32];
  const int tid = threadIdx.x;
  const int w = tid >> 6, lane = tid & 63, g = lane >> 4, li = lane & 15;
  const int ntn = N >> 7;
  const int bt = blockIdx.x / ntn;
  const int m0 = bt << 7, n0 = (blockIdx.x - bt * ntn) << 7;
  const int wm = (w >> 1) << 6, wn = (w & 1) << 6;
  f32x4 acc[4][4];
  #pragma unroll
  for (int i = 0; i < 4; i++)
    #pragma unroll
    for (int j = 0; j < 4; j++)
      #pragma unroll
      for (int r = 0; r < 4; r++) acc[i][j][r] = 0.f;

  for (int k0 = 0; k0 < K; k0 += 32) {
    __syncthreads();
    #pragma unroll
    for (int j = 0; j < 2; j++) {
      int c = (j << 8) + tid;
      int row = c >> 2, sl = c & 3;
      int col = k0 + ((sl ^ (row & 3)) << 3);
      gl2l(A + (size_t)(m0 + row) * lda + col, As + ((c - lane) << 3));
      gl2l(W + (size_t)(n0 + row) * ldw + col, Bs + ((c - lane) << 3));
    }
    __syncthreads();
    bf16x8 af[4], bw[4];
    #pragma unroll
    for (int i = 0; i < 4; i++) {
      int ra = wm + (i << 4) + li;
      af[i] = *(const bf16x8*)(As + ra * 32 + ((g ^ (ra & 3)) << 3));
      int rb = wn + (i << 4) + li;
      bw[i] = *(const bf16x8*)(Bs + rb * 32 + ((g ^ (rb & 3)) << 3));
    }
    #pragma unroll
    for (int i = 0; i < 4; i++)
      #pragma unroll
      for (int j = 0; j < 4; j++)
        acc[i][j] = __builtin_amdgcn_mfma_f32_16x16x32_bf16(af[i], bw[j], acc[i][j], 0, 0, 0);
  }
  #pragma unroll
  for (int j = 0; j < 4; j++) {
    int n = n0 + wn + (j << 4) + li;
    float bias = bias1[n];
    if (MODE == 3) bias += bias2[n];
    #pragma unroll
    for (int i = 0; i < 4; i++) {
      #pragma unroll
      for (int r = 0; r < 4; r++) {
        int m = m0 + wm + (i << 4) + (g << 2) + r;
        float v = acc[i][j][r] + bias;
        if (MODE == 1) v = 0.5f * v * (1.f + erff(v * 0.70710678118654752f));
        if (MODE == 3) {
          ((float*)out)[(size_t)m * N + n] = v;
        } else if (MODE == 2) {   // v_ws: [B][H][L][64]
          int bb = m >> 11, l = m & 2047, hh = n >> 6, cc = n & 63;
          ((__bf16*)out)[((((size_t)bb * Hh + hh) * Ll + l) << 6) + cc] = (__bf16)v;
        } else {
          ((__bf16*)out)[(size_t)m * N + n] = (__bf16)v;
        }
      }
    }
  }
}

// ---------------- build q / k (fused tiny position-encoder matmul + trig) ----------------
// q_ws/k_ws rows are 256 bf16 = 32 16B-chunks, chunk-index XOR'd with (row&7) (pre-swizzle).
__launch_bounds__(256)
__global__ void build_q(const __bf16* __restrict__ x1, const __bf16* __restrict__ x2,
                        const float* __restrict__ xp,
                        const float* __restrict__ pw1, const float* __restrict__ pb1,
                        const float* __restrict__ pw2, const float* __restrict__ pb2,
                        __bf16* __restrict__ q_ws) {
  const int t = blockIdx.x;
  const int b = t >> 11, n = t & 2047;
  const float p0 = xp[(size_t)t*4], p1 = xp[(size_t)t*4+1], p2 = xp[(size_t)t*4+2], p3 = xp[(size_t)t*4+3];
  for (int e = threadIdx.x; e < Ee; e += 256) {
    float a1 = pw1[e*4]*p0 + pw1[e*4+1]*p1 + pw1[e*4+2]*p2 + pw1[e*4+3]*p3 + pb1[e];
    float a2 = pw2[e*4]*p0 + pw2[e*4+1]*p1 + pw2[e*4+2]*p2 + pw2[e*4+3]*p3 + pb2[e];
    float s1, c1, s2, c2;
    __sincosf(a1, &s1, &c1); __sincosf(a2, &s2, &c2);
    float xv1 = (float)x1[(size_t)t * Ee + e];
    float xv2 = (float)x2[(size_t)t * Ee + e];
    const int hh = e >> 6, cc = e & 63, ch = cc >> 3, sub = cc & 7, k = n & 7;
    __bf16* base = q_ws + ((((size_t)b * Hh + hh) * Nn + n) << 8);
    base[(((ch     ) ^ k) << 3) | sub] = (__bf16)(xv1 * c1);
    base[(((ch +  8) ^ k) << 3) | sub] = (__bf16)(xv1 * s1);
    base[(((ch + 16) ^ k) << 3) | sub] = (__bf16)(xv2 * c2);
    base[(((ch + 24) ^ k) << 3) | sub] = (__bf16)(xv2 * s2);
  }
}

__launch_bounds__(256)
__global__ void build_k(const __bf16* __restrict__ y1, const float* __restrict__ yp,
                        const float* __restrict__ pw1, const float* __restrict__ pw2,
                        __bf16* __restrict__ k_ws) {
  const int t = blockIdx.x;
  const int b = t >> 11, l = t & 2047;
  const float p0 = yp[(size_t)t*4], p1 = yp[(size_t)t*4+1], p2 = yp[(size_t)t*4+2], p3 = yp[(size_t)t*4+3];
  for (int e = threadIdx.x; e < Ee; e += 256) {
    float a1 = pw1[e*4]*p0 + pw1[e*4+1]*p1 + pw1[e*4+2]*p2 + pw1[e*4+3]*p3;  // no bias
    float a2 = pw2[e*4]*p0 + pw2[e*4+1]*p1 + pw2[e*4+2]*p2 + pw2[e*4+3]*p3;
    float s1, c1, s2, c2;
    __sincosf(a1, &s1, &c1); __sincosf(a2, &s2, &c2);
    float yv = (float)y1[(size_t)t * Ee + e];
    const int hh = e >> 6, cc = e & 63, ch = cc >> 3, sub = cc & 7, k = l & 7;
    __bf16* base = k_ws + ((((size_t)b * Hh + hh) * Ll + l) << 8);
    base[(((ch     ) ^ k) << 3) | sub] = (__bf16)(yv * c1);
    base[(((ch +  8) ^ k) << 3) | sub] = (__bf16)(yv * s1);
    base[(((ch + 16) ^ k) << 3) | sub] = (__bf16)c2;    // raw position code
    base[(((ch + 24) ^ k) << 3) | sub] = (__bf16)s2;
  }
}

// ---------------- attention pass 1: per-row stats m, s=sum e, t=sum e*mask ----------------
__launch_bounds__(256)
__global__ void attn_stats(const __bf16* __restrict__ q_ws, const __bf16* __restrict__ k_ws,
                           const float* __restrict__ mask,
                           float* __restrict__ sm, float* __restrict__ ss, float* __restrict__ st) {
  __shared__ __align__(16) __bf16 kq[64 * 256];
  const int tid = threadIdx.x, w = tid >> 6, lane = tid & 63, g = lane >> 4, li = lane & 15;
  const int bh = blockIdx.x & 31, nt = blockIdx.x >> 5;
  const int n0 = nt << 6;
  const __bf16* qb = q_ws + (((size_t)bh * Nn + n0) << 8);
  #pragma unroll
  for (int j = 0; j < 8; j++) {
    int c = (j << 8) + tid;
    gl2l(qb + (size_t)(c >> 5) * 256 + ((c & 31) << 3), kq + ((c - lane) << 3));
  }
  __syncthreads();
  bf16x8 aq[8];
  const int qrow = (w << 4) + li;
  #pragma unroll
  for (int s = 0; s < 8; s++) {
    int cc = (s << 2) + g;
    aq[s] = *(const bf16x8*)(kq + qrow * 256 + ((cc ^ (qrow & 7)) << 3));
  }
  float m[4], sa[4], ta[4];
  #pragma unroll
  for (int r = 0; r < 4; r++) { m[r] = -1e30f; sa[r] = 0.f; ta[r] = 0.f; }
  __syncthreads();
  const __bf16* kb = k_ws + (((size_t)bh * Ll) << 8);
  for (int lt = 0; lt < 32; lt++) {
    const int l0 = lt << 6;
    #pragma unroll
    for (int j = 0; j < 8; j++) {
      int c = (j << 8) + tid;
      gl2l(kb + (size_t)(l0 + (c >> 5)) * 256 + ((c & 31) << 3), kq + ((c - lane) << 3));
    }
    __syncthreads();
    f32x4 Cs[4];
    #pragma unroll
    for (int lb = 0; lb < 4; lb++) {
      f32x4 a; a[0] = a[1] = a[2] = a[3] = 0.f;
      const int kr = (lb << 4) + li;
      #pragma unroll
      for (int s = 0; s < 8; s++) {
        int cc = (s << 2) + g;
        bf16x8 bk = *(const bf16x8*)(kq + kr * 256 + ((cc ^ (kr & 7)) << 3));
        a = __builtin_amdgcn_mfma_f32_16x16x32_bf16(aq[s], bk, a, 0, 0, 0);
      }
      Cs[lb] = a;
    }
    #pragma unroll
    for (int r = 0; r < 4; r++) {
      const int n = n0 + (w << 4) + (g << 2) + r;
      float v0 = Cs[0][r]*SCALE, v1 = Cs[1][r]*SCALE, v2 = Cs[2][r]*SCALE, v3 = Cs[3][r]*SCALE;
      float tmax = fmaxf(fmaxf(v0, v1), fmaxf(v2, v3));
      #pragma unroll
      for (int o = 1; o < 16; o <<= 1) tmax = fmaxf(tmax, __shfl_xor(tmax, o));
      float nm = fmaxf(m[r], tmax);
      float e0 = __expf(v0 - nm), e1 = __expf(v1 - nm), e2 = __expf(v2 - nm), e3 = __expf(v3 - nm);
      const float* mp = mask + (size_t)n * Ll + l0 + li;
      float es = e0 + e1 + e2 + e3;
      float em = e0 * mp[0] + e1 * mp[16] + e2 * mp[32] + e3 * mp[48];
      #pragma unroll
      for (int o = 1; o < 16; o <<= 1) { es += __shfl_xor(es, o); em += __shfl_xor(em, o); }
      float f = __expf(m[r] - nm);
      sa[r] = sa[r] * f + es; ta[r] = ta[r] * f + em; m[r] = nm;
    }
    __syncthreads();
  }
  if (li == 0) {
    #pragma unroll
    for (int r = 0; r < 4; r++) {
      size_t idx = (size_t)bh * Nn + n0 + (w << 4) + (g << 2) + r;
      sm[idx] = m[r]; ss[idx] = sa[r]; st[idx] = ta[r];
    }
  }
}

// ---------------- attention pass 2: final attn out + PV + attn@yp ----------------
__launch_bounds__(256)
__global__ void attn_apply(const __bf16* __restrict__ q_ws, const __bf16* __restrict__ k_ws,
                           const __bf16* __restrict__ v_ws,
                           const float* __restrict__ yp, const float* __restrict__ xp,
                           const float* __restrict__ mask,
                           const float* __restrict__ sm, const float* __restrict__ ss,
                           const float* __restrict__ st,
                           float* __restrict__ attn_out, __bf16* __restrict__ avz) {
  __shared__ __align__(16) __bf16 kq[64 * 256];
  __shared__ __align__(16) __bf16 vraw[64 * 64];
  __shared__ __align__(16) __bf16 vT[64 * 72];
  __shared__ __align__(16) __bf16 pT[64 * 64];
  __shared__ __align__(16) __bf16 ypT[16 * 72];
  const int tid = threadIdx.x, w = tid >> 6, lane = tid & 63, g = lane >> 4, li = lane & 15;
  const int bh = blockIdx.x & 31, nt = blockIdx.x >> 5;
  const int b = bh >> 4, h = bh & 15;
  const int n0 = nt << 6;
  for (int i = tid; i < 12 * 72; i += 256) ypT[288 + i] = (__bf16)0.f;  // zero pad rows 4..15
  const __bf16* qb = q_ws + (((size_t)bh * Nn + n0) << 8);
  #pragma unroll
  for (int j = 0; j < 8; j++) {
    int c = (j << 8) + tid;
    gl2l(qb + (size_t)(c >> 5) * 256 + ((c & 31) << 3), kq + ((c - lane) << 3));
  }
  __syncthreads();
  bf16x8 aq[8];
  const int qrow = (w << 4) + li;
  #pragma unroll
  for (int s = 0; s < 8; s++) {
    int cc = (s << 2) + g;
    aq[s] = *(const bf16x8*)(kq + qrow * 256 + ((cc ^ (qrow & 7)) << 3));
  }
  float m[4], dinv[4];
  #pragma unroll
  for (int r = 0; r < 4; r++) {
    size_t idx = (size_t)bh * Nn + n0 + (w << 4) + (g << 2) + r;
    m[r] = sm[idx];
    dinv[r] = 1.f / (st[idx] + 1e-8f * ss[idx]);
  }
  f32x4 accv[4]; f32x4 accp;
  #pragma unroll
  for (int cb = 0; cb < 4; cb++) { accv[cb][0]=accv[cb][1]=accv[cb][2]=accv[cb][3]=0.f; }
  accp[0] = accp[1] = accp[2] = accp[3] = 0.f;
  __syncthreads();
  const __bf16* kb = k_ws + (((size_t)bh * Ll) << 8);
  const __bf16* vbp = v_ws + (((size_t)bh * Ll) << 6);
  for (int lt = 0; lt < 32; lt++) {
    const int l0 = lt << 6;
    #pragma unroll
    for (int j = 0; j < 8; j++) {
      int c = (j << 8) + tid;
      gl2l(kb + (size_t)(l0 + (c >> 5)) * 256 + ((c & 31) << 3), kq + ((c - lane) << 3));
    }
    #pragma unroll
    for (int j = 0; j < 2; j++) {
      int c = (j << 8) + tid;
      gl2l(vbp + (size_t)(l0 + (c >> 3)) * 64 + ((c & 7) << 3), vraw + ((c - lane) << 3));
    }
    {
      int l = tid & 63, dd = tid >> 6;
      float vy = yp[((size_t)b * Ll + l0 + l) * 4 + dd];
      ypT[dd * 72 + l] = (__bf16)vy;
    }
    __syncthreads();
    for (int i = tid; i < 4096; i += 256) {      // transpose v for B-operand reads
      int l = i >> 6, c = i & 63;
      vT[c * 72 + l] = vraw[i];
    }
    f32x4 Cs[4];
    #pragma unroll
    for (int lb = 0; lb < 4; lb++) {
      f32x4 a; a[0] = a[1] = a[2] = a[3] = 0.f;
      const int kr = (lb << 4) + li;
      #pragma unroll
      for (int s = 0; s < 8; s++) {
        int cc = (s << 2) + g;
        bf16x8 bk = *(const bf16x8*)(kq + kr * 256 + ((cc ^ (kr & 7)) << 3));
        a = __builtin_amdgcn_mfma_f32_16x16x32_bf16(aq[s], bk, a, 0, 0, 0);
      }
      Cs[lb] = a;
    }
    #pragma unroll
    for (int lb = 0; lb < 4; lb++) {
      #pragma unroll
      for (int r = 0; r < 4; r++) {
        const int nl = (w << 4) + (g << 2) + r;
        const int n = n0 + nl;
        const int lc = (lb << 4) + li;
        float p = __expf(Cs[lb][r] * SCALE - m[r]) * mask[(size_t)n * Ll + l0 + lc] * dinv[r];
        attn_out[(((size_t)bh) << 22) + (((size_t)n) << 11) + l0 + lc] = p;
        pT[nl * 64 + ((((lc >> 3) ^ (nl & 7)) << 3) | (lc & 7))] = (__bf16)p;
      }
    }
    __syncthreads();
    #pragma unroll
    for (int kc = 0; kc < 2; kc++) {
      const int ar = (w << 4) + li;
      int lcc = (kc << 2) + g;
      bf16x8 pa = *(const bf16x8*)(pT + ar * 64 + ((lcc ^ (ar & 7)) << 3));
      #pragma unroll
      for (int cb = 0; cb < 4; cb++) {
        bf16x8 vv = *(const bf16x8*)(vT + ((cb << 4) + li) * 72 + (kc << 5) + (g << 3));
        accv[cb] = __builtin_amdgcn_mfma_f32_16x16x32_bf16(pa, vv, accv[cb], 0, 0, 0);
      }
      bf16x8 yy = *(const bf16x8*)(ypT + li * 72 + (kc << 5) + (g << 3));
      accp = __builtin_amdgcn_mfma_f32_16x16x32_bf16(pa, yy, accp, 0, 0, 0);
    }
    __syncthreads();
  }
  #pragma unroll
  for (int cb = 0; cb < 4; cb++) {
    #pragma unroll
    for (int r = 0; r < 4; r++) {
      const int n = n0 + (w << 4) + (g << 2) + r;
      avz[((size_t)b * Nn + n) * 1088 + (h << 6) + (cb << 4) + li] = (__bf16)accv[cb][r];
    }
  }
  if (li < 4) {
    #pragma unroll
    for (int r = 0; r < 4; r++) {
      const int n = n0 + (w << 4) + (g << 2) + r;
      float z = accp[r] - xp[((size_t)b * Nn + n) * 4 + li];
      avz[((size_t)b * Nn + n) * 1088 + 1024 + (h << 2) + li] = (__bf16)z;
    }
  }
}

// ---------------- host ----------------
extern "C" void kernel_launch(void* const* d_in, const int* in_sizes, int n_in,
                              void* d_out, int out_size, void* d_ws, size_t ws_size,
                              hipStream_t stream) {
  (void)in_sizes; (void)n_in; (void)out_size; (void)ws_size;
  const float* x       = (const float*)d_in[0];
  const float* xp      = (const float*)d_in[1];
  const float* y       = (const float*)d_in[2];
  const float* yp      = (const float*)d_in[3];
  const float* mask    = (const float*)d_in[4];
  const float* p_w1    = (const float*)d_in[5];
  const float* p_b1    = (const float*)d_in[6];
  const float* p_w2    = (const float*)d_in[7];
  const float* p_b2    = (const float*)d_in[8];
  const float* q_ln_g  = (const float*)d_in[9];
  const float* q_ln_b  = (const float*)d_in[10];
  const float* q_m1_w1 = (const float*)d_in[11];
  const float* q_m1_b1 = (const float*)d_in[12];
  const float* q_m1_w2 = (const float*)d_in[13];
  const float* q_m1_b2 = (const float*)d_in[14];
  const float* q_m2_w1 = (const float*)d_in[15];
  const float* q_m2_b1 = (const float*)d_in[16];
  const float* q_m2_w2 = (const float*)d_in[17];
  const float* q_m2_b2 = (const float*)d_in[18];
  const float* k_ln_g  = (const float*)d_in[19];
  const float* k_ln_b  = (const float*)d_in[20];
  const float* k_m1_w1 = (const float*)d_in[21];
  const float* k_m1_b1 = (const float*)d_in[22];
  const float* k_m1_w2 = (const float*)d_in[23];
  const float* k_m1_b2 = (const float*)d_in[24];
  const float* v_ln_g  = (const float*)d_in[25];
  const float* v_ln_b  = (const float*)d_in[26];
  const float* v_w     = (const float*)d_in[27];
  const float* v_b     = (const float*)d_in[28];
  const float* proj1_w = (const float*)d_in[29];
  const float* proj1_b = (const float*)d_in[30];
  const float* proj2_w = (const float*)d_in[31];
  const float* proj2_b = (const float*)d_in[32];

  char* ws = (char*)d_ws;
  __bf16* xn   = (__bf16*)(ws + OFF_XN);
  __bf16* ynk  = (__bf16*)(ws + OFF_YNK);
  __bf16* ynv  = (__bf16*)(ws + OFF_YNV);
  __bf16* hbuf = (__bf16*)(ws + OFF_H);
  __bf16* x1   = (__bf16*)(ws + OFF_X1);
  __bf16* x2   = (__bf16*)(ws + OFF_X2);
  __bf16* y1   = (__bf16*)(ws + OFF_Y1);
  __bf16* q_ws = (__bf16*)(ws + OFF_QWS);
  __bf16* k_ws = (__bf16*)(ws + OFF_KWS);
  __bf16* v_ws = (__bf16*)(ws + OFF_VWS);
  float*  sm   = (float*)(ws + OFF_SM);
  float*  ss   = (float*)(ws + OFF_SS);
  float*  st   = (float*)(ws + OFF_ST);
  __bf16* avz  = (__bf16*)(ws + OFF_AVZ);
  __bf16* w11  = (__bf16*)(ws + OFF_W11);
  __bf16* w12  = (__bf16*)(ws + OFF_W12);
  __bf16* w21  = (__bf16*)(ws + OFF_W21);
  __bf16* w22  = (__bf16*)(ws + OFF_W22);
  __bf16* wk1  = (__bf16*)(ws + OFF_WK1);
  __bf16* wk2  = (__bf16*)(ws + OFF_WK2);
  __bf16* wv   = (__bf16*)(ws + OFF_WV);
  __bf16* wp   = (__bf16*)(ws + OFF_WP);

  float* out0     = (float*)d_out;
  float* attn_out = out0 + (size_t)4194304;
  float* xp_out   = out0 + (size_t)138412032;

  // weight conversions
  cvt_bf16<<<2048, 256, 0, stream>>>(q_m1_w1, w11, 524288);
  cvt_bf16<<<2048, 256, 0, stream>>>(q_m1_w2, w12, 524288);
  cvt_bf16<<<2048, 256, 0, stream>>>(q_m2_w1, w21, 524288);
  cvt_bf16<<<2048, 256, 0, stream>>>(q_m2_w2, w22, 524288);
  cvt_bf16<<<2048, 256, 0, stream>>>(k_m1_w1, wk1, 524288);
  cvt_bf16<<<2048, 256, 0, stream>>>(k_m1_w2, wk2, 524288);
  cvt_bf16<<<1024, 256, 0, stream>>>(v_w, wv, 262144);
  cvt_proj<<<1024, 256, 0, stream>>>(proj1_w, proj2_w, wp);

  // layernorms
  ln_kernel<<<4096, 256, 0, stream>>>(x, q_ln_g, q_ln_b, xn);
  ln_kernel<<<4096, 256, 0, stream>>>(y, k_ln_g, k_ln_b, ynk);
  ln_kernel<<<4096, 256, 0, stream>>>(y, v_ln_g, v_ln_b, ynv);

  // encoders
  gemm_nt<1><<<512, 256, 0, stream>>>(xn, 1024, w11, 1024, q_m1_b1, nullptr, hbuf, 4096, 2048, 1024);
  gemm_nt<0><<<256, 256, 0, stream>>>(hbuf, 2048, w12, 2048, q_m1_b2, nullptr, x1, 4096, 1024, 2048);
  gemm_nt<1><<<512, 256, 0, stream>>>(xn, 1024, w21, 1024, q_m2_b1, nullptr, hbuf, 4096, 2048, 1024);
  gemm_nt<0><<<256, 256, 0, stream>>>(hbuf, 2048, w22, 2048, q_m2_b2, nullptr, x2, 4096, 1024, 2048);
  gemm_nt<1><<<512, 256, 0, stream>>>(ynk, 1024, wk1, 1024, k_m1_b1, nullptr, hbuf, 4096, 2048, 1024);
  gemm_nt<0><<<256, 256, 0, stream>>>(hbuf, 2048, wk2, 2048, k_m1_b2, nullptr, y1, 4096, 1024, 2048);
  gemm_nt<2><<<256, 256, 0, stream>>>(ynv, 1024, wv, 1024, v_b, nullptr, v_ws, 4096, 1024, 1024);

  build_q<<<4096, 256, 0, stream>>>(x1, x2, xp, p_w1, p_b1, p_w2, p_b2, q_ws);
  build_k<<<4096, 256, 0, stream>>>(y1, yp, p_w1, p_w2, k_ws);

  // attention
  attn_stats<<<1024, 256, 0, stream>>>(q_ws, k_ws, mask, sm, ss, st);
  attn_apply<<<1024, 256, 0, stream>>>(q_ws, k_ws, v_ws, yp, xp, mask, sm, ss, st, attn_out, avz);

  // fused output projection: out0 = avz @ [proj1_w | proj2_w]^T + proj1_b + proj2_b
  gemm_nt<3><<<256, 256, 0, stream>>>(avz, 1088, wp, 1088, proj1_b, proj2_b, out0, 4096, 1024, 1088);

  // third output: xp passthrough
  hipMemcpyAsync(xp_out, d_in[1], 65536, hipMemcpyDeviceToDevice, stream);
}

// Round 2
// 852.628 us; speedup vs baseline: 1.0491x; 1.0491x over previous
//
#include <hip/hip_runtime.h>
#include <math.h>
#include <stdint.h>

#define DEV static __device__ __forceinline__

typedef __bf16 bf16x8 __attribute__((ext_vector_type(8)));
typedef __bf16 bf16x4v __attribute__((ext_vector_type(4)));
typedef float f32x4 __attribute__((ext_vector_type(4)));

// problem dims
constexpr int Bb = 2, Nn = 2048, Ll = 2048, Ee = 1024, Hh = 16;
constexpr float SCALE = 0.0625f;   // (4C)^-0.5 = 1/16

// ---------------- workspace layout (bytes) ----------------
constexpr size_t OFF_XN  = 0;                         // [4096][1024] bf16
constexpr size_t OFF_YNK = OFF_XN  + 8388608;
constexpr size_t OFF_YNV = OFF_YNK + 8388608;
constexpr size_t OFF_H   = OFF_YNV + 8388608;         // [4096][2048] bf16 (reused 3x)
constexpr size_t OFF_X1  = OFF_H   + 16777216;
constexpr size_t OFF_X2  = OFF_X1  + 8388608;
constexpr size_t OFF_Y1  = OFF_X2  + 8388608;
constexpr size_t OFF_QWS = OFF_Y1  + 8388608;         // [B][H][N][256] bf16, pre-swizzled
constexpr size_t OFF_KWS = OFF_QWS + 33554432;        // [B][H][L][256] bf16, pre-swizzled
constexpr size_t OFF_VWS = OFF_KWS + 33554432;        // vT: [B*H][64][2048] bf16
constexpr size_t OFF_DNV = OFF_VWS + 8388608;         // f32 [B*H*N] dinv
constexpr size_t OFF_YPT = OFF_DNV + 262144;          // ypT [B][4][2048] bf16
constexpr size_t OFF_ST  = OFF_YPT + 262144;          // (spare)
constexpr size_t OFF_AVZ = OFF_ST  + 262144;          // [4096][1088] bf16 : [attn_v | z]
constexpr size_t OFF_W11 = OFF_AVZ + 8912896;         // bf16 weights
constexpr size_t OFF_W12 = OFF_W11 + 4194304;
constexpr size_t OFF_W21 = OFF_W12 + 4194304;
constexpr size_t OFF_W22 = OFF_W21 + 4194304;
constexpr size_t OFF_WK1 = OFF_W22 + 4194304;
constexpr size_t OFF_WK2 = OFF_WK1 + 4194304;
constexpr size_t OFF_WV  = OFF_WK2 + 4194304;
constexpr size_t OFF_WP  = OFF_WV  + 2097152;         // [1024][1088] bf16 fused proj
constexpr size_t OFF_EM  = OFF_WP  + 2228224;         // em bf16 [B*H][2048][2048] = 268MB

DEV void gl2l(const void* g, void* l) {
  __builtin_amdgcn_global_load_lds((const __attribute__((address_space(1))) void*)g,
                                   (__attribute__((address_space(3))) void*)l, 16, 0, 0);
}

// ---------------- dtype conversion ----------------
__launch_bounds__(256)
__global__ void cvt_bf16(const float* __restrict__ s, __bf16* __restrict__ d, int n4) {
  int i = blockIdx.x * 256 + threadIdx.x;
  if (i < n4) {
    float4 v = ((const float4*)s)[i];
    bf16x4v o; o[0]=(__bf16)v.x; o[1]=(__bf16)v.y; o[2]=(__bf16)v.z; o[3]=(__bf16)v.w;
    ((bf16x4v*)d)[i] = o;
  }
}

__launch_bounds__(256)
__global__ void cvt_proj(const float* __restrict__ w1, const float* __restrict__ w2,
                         __bf16* __restrict__ d) {
  for (size_t i = blockIdx.x * 256ul + threadIdx.x; i < 1024ul * 1088ul; i += 262144ul) {
    size_t row = i / 1088, col = i - row * 1088;
    float v = (col < 1024) ? w1[row * 1024 + col] : w2[(row << 6) + (col - 1024)];
    d[i] = (__bf16)v;
  }
}

// yp [B][L][4] f32 -> ypT [B][4][L] bf16
__launch_bounds__(256)
__global__ void yp_tr(const float* __restrict__ yp, __bf16* __restrict__ ypT) {
  int i = blockIdx.x * 256 + threadIdx.x;   // 16384
  int b = i >> 13, d = (i >> 11) & 3, l = i & 2047;
  ypT[i] = (__bf16)yp[(((size_t)b << 11) + l) * 4 + d];
}

// ---------------- LayerNorm (one block per token) ----------------
__launch_bounds__(256)
__global__ void ln_kernel(const float* __restrict__ x, const float* __restrict__ gam,
                          const float* __restrict__ bet, __bf16* __restrict__ out) {
  const int t = blockIdx.x, tid = threadIdx.x;
  const float4 v = ((const float4*)(x + (size_t)t * Ee))[tid];
  float s = v.x + v.y + v.z + v.w;
  float q = v.x*v.x + v.y*v.y + v.z*v.z + v.w*v.w;
  #pragma unroll
  for (int o = 32; o > 0; o >>= 1) { s += __shfl_down(s, o); q += __shfl_down(q, o); }
  __shared__ float ls[4], lq[4];
  if ((tid & 63) == 0) { ls[tid >> 6] = s; lq[tid >> 6] = q; }
  __syncthreads();
  s = ls[0] + ls[1] + ls[2] + ls[3];
  q = lq[0] + lq[1] + lq[2] + lq[3];
  const float mu = s * (1.f / Ee);
  const float rstd = rsqrtf(q * (1.f / Ee) - mu * mu + 1e-5f);
  const int e0 = tid << 2;
  bf16x4v o;
  o[0] = (__bf16)((v.x - mu) * rstd * gam[e0]   + bet[e0]);
  o[1] = (__bf16)((v.y - mu) * rstd * gam[e0+1] + bet[e0+1]);
  o[2] = (__bf16)((v.z - mu) * rstd * gam[e0+2] + bet[e0+2]);
  o[3] = (__bf16)((v.w - mu) * rstd * gam[e0+3] + bet[e0+3]);
  *(bf16x4v*)(out + (size_t)t * Ee + e0) = o;
}

// ---------------- NT GEMM: C[m,n] = sum_k A[m,k] * W[n,k] (+bias) ----------------
// MODE: 0 = bf16 out + bias; 1 = + GELU(exact); 2 = bf16 vT layout; 3 = f32 out + bias1+bias2
template<int MODE>
__launch_bounds__(256)
__global__ void gemm_nt(const __bf16* __restrict__ A, int lda,
                        const __bf16* __restrict__ W, int ldw,
                        const float* __restrict__ bias1, const float* __restrict__ bias2,
                        void* __restrict__ out, int M, int N, int K) {
  __shared__ __align__(16) __bf16 As[128 * 32];
  __shared__ __align__(16) __bf16 Bs[128 * 32];
  const int tid = threadIdx.x;
  const int w = tid >> 6, lane = tid & 63, g = lane >> 4, li = lane & 15;
  const int ntn = N >> 7;
  const int bt = blockIdx.x / ntn;
  const int m0 = bt << 7, n0 = (blockIdx.x - bt * ntn) << 7;
  const int wm = (w >> 1) << 6, wn = (w & 1) << 6;
  f32x4 acc[4][4];
  #pragma unroll
  for (int i = 0; i < 4; i++)
    #pragma unroll
    for (int j = 0; j < 4; j++)
      #pragma unroll
      for (int r = 0; r < 4; r++) acc[i][j][r] = 0.f;

  for (int k0 = 0; k0 < K; k0 += 32) {
    __syncthreads();
    #pragma unroll
    for (int j = 0; j < 2; j++) {
      int c = (j << 8) + tid;
      int row = c >> 2, sl = c & 3;
      int col = k0 + ((sl ^ (row & 3)) << 3);
      gl2l(A + (size_t)(m0 + row) * lda + col, As + ((c - lane) << 3));
      gl2l(W + (size_t)(n0 + row) * ldw + col, Bs + ((c - lane) << 3));
    }
    __syncthreads();
    bf16x8 af[4], bw[4];
    #pragma unroll
    for (int i = 0; i < 4; i++) {
      int ra = wm + (i << 4) + li;
      af[i] = *(const bf16x8*)(As + ra * 32 + ((g ^ (ra & 3)) << 3));
      int rb = wn + (i << 4) + li;
      bw[i] = *(const bf16x8*)(Bs + rb * 32 + ((g ^ (rb & 3)) << 3));
    }
    #pragma unroll
    for (int i = 0; i < 4; i++)
      #pragma unroll
      for (int j = 0; j < 4; j++)
        acc[i][j] = __builtin_amdgcn_mfma_f32_16x16x32_bf16(af[i], bw[j], acc[i][j], 0, 0, 0);
  }
  #pragma unroll
  for (int j = 0; j < 4; j++) {
    int n = n0 + wn + (j << 4) + li;
    float bias = bias1[n];
    if (MODE == 3) bias += bias2[n];
    #pragma unroll
    for (int i = 0; i < 4; i++) {
      #pragma unroll
      for (int r = 0; r < 4; r++) {
        int m = m0 + wm + (i << 4) + (g << 2) + r;
        float v = acc[i][j][r] + bias;
        if (MODE == 1) v = 0.5f * v * (1.f + erff(v * 0.70710678118654752f));
        if (MODE == 3) {
          ((float*)out)[(size_t)m * N + n] = v;
        } else if (MODE == 2) {   // vT: [B*H][64][2048]
          int bb = m >> 11, l = m & 2047, hh = n >> 6, cc = n & 63;
          ((__bf16*)out)[(((size_t)(bb * Hh + hh) * 64 + cc) << 11) + l] = (__bf16)v;
        } else {
          ((__bf16*)out)[(size_t)m * N + n] = (__bf16)v;
        }
      }
    }
  }
}

// ---------------- build q / k (fused tiny position-encoder matmul + trig) ----------------
__launch_bounds__(256)
__global__ void build_q(const __bf16* __restrict__ x1, const __bf16* __restrict__ x2,
                        const float* __restrict__ xp,
                        const float* __restrict__ pw1, const float* __restrict__ pb1,
                        const float* __restrict__ pw2, const float* __restrict__ pb2,
                        __bf16* __restrict__ q_ws) {
  const int t = blockIdx.x;
  const int b = t >> 11, n = t & 2047;
  const float p0 = xp[(size_t)t*4], p1 = xp[(size_t)t*4+1], p2 = xp[(size_t)t*4+2], p3 = xp[(size_t)t*4+3];
  for (int e = threadIdx.x; e < Ee; e += 256) {
    float a1 = pw1[e*4]*p0 + pw1[e*4+1]*p1 + pw1[e*4+2]*p2 + pw1[e*4+3]*p3 + pb1[e];
    float a2 = pw2[e*4]*p0 + pw2[e*4+1]*p1 + pw2[e*4+2]*p2 + pw2[e*4+3]*p3 + pb2[e];
    float s1, c1, s2, c2;
    __sincosf(a1, &s1, &c1); __sincosf(a2, &s2, &c2);
    float xv1 = (float)x1[(size_t)t * Ee + e];
    float xv2 = (float)x2[(size_t)t * Ee + e];
    const int hh = e >> 6, cc = e & 63, ch = cc >> 3, sub = cc & 7, k = n & 7;
    __bf16* base = q_ws + ((((size_t)b * Hh + hh) * Nn + n) << 8);
    base[(((ch     ) ^ k) << 3) | sub] = (__bf16)(xv1 * c1);
    base[(((ch +  8) ^ k) << 3) | sub] = (__bf16)(xv1 * s1);
    base[(((ch + 16) ^ k) << 3) | sub] = (__bf16)(xv2 * c2);
    base[(((ch + 24) ^ k) << 3) | sub] = (__bf16)(xv2 * s2);
  }
}

__launch_bounds__(256)
__global__ void build_k(const __bf16* __restrict__ y1, const float* __restrict__ yp,
                        const float* __restrict__ pw1, const float* __restrict__ pw2,
                        __bf16* __restrict__ k_ws) {
  const int t = blockIdx.x;
  const int b = t >> 11, l = t & 2047;
  const float p0 = yp[(size_t)t*4], p1 = yp[(size_t)t*4+1], p2 = yp[(size_t)t*4+2], p3 = yp[(size_t)t*4+3];
  for (int e = threadIdx.x; e < Ee; e += 256) {
    float a1 = pw1[e*4]*p0 + pw1[e*4+1]*p1 + pw1[e*4+2]*p2 + pw1[e*4+3]*p3;  // no bias
    float a2 = pw2[e*4]*p0 + pw2[e*4+1]*p1 + pw2[e*4+2]*p2 + pw2[e*4+3]*p3;
    float s1, c1, s2, c2;
    __sincosf(a1, &s1, &c1); __sincosf(a2, &s2, &c2);
    float yv = (float)y1[(size_t)t * Ee + e];
    const int hh = e >> 6, cc = e & 63, ch = cc >> 3, sub = cc & 7, k = l & 7;
    __bf16* base = k_ws + ((((size_t)b * Hh + hh) * Ll + l) << 8);
    base[(((ch     ) ^ k) << 3) | sub] = (__bf16)(yv * c1);
    base[(((ch +  8) ^ k) << 3) | sub] = (__bf16)(yv * s1);
    base[(((ch + 16) ^ k) << 3) | sub] = (__bf16)c2;    // raw position code
    base[(((ch + 24) ^ k) << 3) | sub] = (__bf16)s2;
  }
}

// ---------------- fused flash attention (single QK^T pass, no max) ----------------
// 256 q-rows/block, 8 waves (32 rows each, 2 frags), KVBLK=32, double-buffered staging.
// Writes: em = exp(s)*mask (bf16) to em_g; dinv per row; avz (PV and attn@yp, scaled).
__launch_bounds__(512, 2)
__global__ void attn_fused(const __bf16* __restrict__ q_ws, const __bf16* __restrict__ k_ws,
                           const __bf16* __restrict__ vT_ws, const __bf16* __restrict__ ypT_g,
                           const float* __restrict__ mask, const float* __restrict__ xp,
                           __bf16* __restrict__ em_g, float* __restrict__ dinv_g,
                           __bf16* __restrict__ avz) {
  __shared__ __align__(16) __bf16 kq[2][32 * 256];   // 32 KB, pre-swizzled rows
  __shared__ __align__(16) __bf16 vt[2][64 * 40];    // padded rows (80B)
  __shared__ __align__(16) __bf16 pT[256 * 40];      // padded rows (80B)
  __shared__ __align__(16) __bf16 ypl[2][16 * 40];
  const int tid = threadIdx.x, w = tid >> 6, lane = tid & 63, g = lane >> 4, li = lane & 15;
  const int bh = blockIdx.x & 31, nt = blockIdx.x >> 5;
  const int b = bh >> 4, h = bh & 15;
  const int n0 = nt << 8;
  const __bf16* qb = q_ws + (((size_t)bh * Nn + n0) << 8);
  const __bf16* kb = k_ws + (((size_t)bh * Ll) << 8);
  const __bf16* vb = vT_ws + ((size_t)bh << 17);
  const __bf16* yb = ypT_g + ((size_t)b << 13);

  // Q fragments direct from (pre-swizzled) global
  bf16x8 aq[2][8];
  #pragma unroll
  for (int rf = 0; rf < 2; rf++) {
    const int nloc = (w << 5) + (rf << 4) + li;
    #pragma unroll
    for (int s = 0; s < 8; s++) {
      int cc = (s << 2) + g;
      aq[rf][s] = *(const bf16x8*)(qb + ((size_t)nloc << 8) + ((cc ^ (nloc & 7)) << 3));
    }
  }
  // zero ypl rows 4..15 (both buffers)
  for (int i = tid; i < 960; i += 512) {
    int buf = i / 480, idx = i - buf * 480;
    ypl[buf][160 + idx] = (__bf16)0.f;
  }
  // prologue: stage tile 0
  {
    const int vc = tid >> 3, vl = (tid & 7) << 2;
    bf16x4v vreg = *(const bf16x4v*)(vb + ((size_t)vc << 11) + vl);
    bf16x4v ypreg;
    if (tid < 32) ypreg = *(const bf16x4v*)(yb + ((size_t)(tid >> 3) << 11) + ((tid & 7) << 2));
    #pragma unroll
    for (int j = 0; j < 2; j++) {
      int c = (j << 9) + tid;
      int row = c >> 5, ch = c & 31;
      gl2l(kb + (size_t)row * 256 + (ch << 3), kq[0] + ((c - lane) << 3));
    }
    *(bf16x4v*)(vt[0] + vc * 40 + vl) = vreg;
    if (tid < 32) *(bf16x4v*)(ypl[0] + (tid >> 3) * 40 + ((tid & 7) << 2)) = ypreg;
  }
  __syncthreads();

  float se[2][4], te[2][4];
  f32x4 accv[2][4], accp[2];
  #pragma unroll
  for (int rf = 0; rf < 2; rf++) {
    #pragma unroll
    for (int r = 0; r < 4; r++) { se[rf][r] = 0.f; te[rf][r] = 0.f; }
    #pragma unroll
    for (int cb = 0; cb < 4; cb++) accv[rf][cb] = (f32x4)0.f;
    accp[rf] = (f32x4)0.f;
  }

  for (int t = 0; t < 64; ++t) {
    const int l0 = t << 5, cur = t & 1, nxt = cur ^ 1;
    const bool more = (t < 63);
    bf16x4v vreg, ypreg;
    if (more) {
      const int l1 = l0 + 32;
      vreg = *(const bf16x4v*)(vb + ((size_t)(tid >> 3) << 11) + l1 + ((tid & 7) << 2));
      if (tid < 32) ypreg = *(const bf16x4v*)(yb + ((size_t)(tid >> 3) << 11) + l1 + ((tid & 7) << 2));
      #pragma unroll
      for (int j = 0; j < 2; j++) {
        int c = (j << 9) + tid;
        int row = c >> 5, ch = c & 31;
        gl2l(kb + (size_t)(l1 + row) * 256 + (ch << 3), kq[nxt] + ((c - lane) << 3));
      }
    }
    // QK^T + exp + mask + sums + pT write (per row-fragment)
    #pragma unroll
    for (int rf = 0; rf < 2; rf++) {
      const int rbase = n0 + (w << 5) + (rf << 4) + (g << 2);
      f32x4 Cs[2];
      #pragma unroll
      for (int lb = 0; lb < 2; lb++) {
        f32x4 a = (f32x4)0.f;
        const int kr = (lb << 4) + li;
        #pragma unroll
        for (int s = 0; s < 8; s++) {
          int cc = (s << 2) + g;
          bf16x8 bk = *(const bf16x8*)(kq[cur] + kr * 256 + ((cc ^ (kr & 7)) << 3));
          a = __builtin_amdgcn_mfma_f32_16x16x32_bf16(aq[rf][s], bk, a, 0, 0, 0);
        }
        Cs[lb] = a;
      }
      #pragma unroll
      for (int lb = 0; lb < 2; lb++) {
        #pragma unroll
        for (int r = 0; r < 4; r++) {
          float e = __expf(Cs[lb][r] * SCALE);
          float mkv = mask[(size_t)(rbase + r) * Ll + l0 + (lb << 4) + li];
          float em = e * mkv;
          se[rf][r] += e; te[rf][r] += em;
          pT[((w << 5) + (rf << 4) + (g << 2) + r) * 40 + (lb << 4) + li] = (__bf16)em;
        }
      }
    }
    asm volatile("s_waitcnt lgkmcnt(0)" ::: "memory");
    __builtin_amdgcn_sched_barrier(0);
    // em global store (vectorized from pT)
    #pragma unroll
    for (int j = 0; j < 2; j++) {
      int q = (j << 6) + lane;
      int row = q >> 2, ch = q & 3;
      bf16x8 pv = *(const bf16x8*)(pT + ((w << 5) + row) * 40 + (ch << 3));
      *(bf16x8*)(em_g + ((size_t)bh << 22) + ((size_t)(n0 + (w << 5) + row) << 11) + l0 + (ch << 3)) = pv;
    }
    // PV + attn@yp
    bf16x8 vv[4];
    #pragma unroll
    for (int cb = 0; cb < 4; cb++)
      vv[cb] = *(const bf16x8*)(vt[cur] + ((cb << 4) + li) * 40 + (g << 3));
    bf16x8 yy = *(const bf16x8*)(ypl[cur] + li * 40 + (g << 3));
    #pragma unroll
    for (int rf = 0; rf < 2; rf++) {
      bf16x8 pa = *(const bf16x8*)(pT + ((w << 5) + (rf << 4) + li) * 40 + (g << 3));
      #pragma unroll
      for (int cb = 0; cb < 4; cb++)
        accv[rf][cb] = __builtin_amdgcn_mfma_f32_16x16x32_bf16(pa, vv[cb], accv[rf][cb], 0, 0, 0);
      accp[rf] = __builtin_amdgcn_mfma_f32_16x16x32_bf16(pa, yy, accp[rf], 0, 0, 0);
    }
    // write staged v/yp for next tile
    if (more) {
      *(bf16x4v*)(vt[nxt] + (tid >> 3) * 40 + ((tid & 7) << 2)) = vreg;
      if (tid < 32) *(bf16x4v*)(ypl[nxt] + (tid >> 3) * 40 + ((tid & 7) << 2)) = ypreg;
    }
    __syncthreads();
  }

  // epilogue: reduce sums, write dinv + avz
  #pragma unroll
  for (int rf = 0; rf < 2; rf++) {
    #pragma unroll
    for (int r = 0; r < 4; r++) {
      float s = se[rf][r], tt = te[rf][r];
      #pragma unroll
      for (int o = 1; o < 16; o <<= 1) { s += __shfl_xor(s, o); tt += __shfl_xor(tt, o); }
      float dinv = 1.f / (tt + 1e-8f * s);
      const int n = n0 + (w << 5) + (rf << 4) + (g << 2) + r;
      if (li == 0) dinv_g[((size_t)bh << 11) + n] = dinv;
      #pragma unroll
      for (int cb = 0; cb < 4; cb++)
        avz[((size_t)b * Nn + n) * 1088 + (h << 6) + (cb << 4) + li] = (__bf16)(accv[rf][cb][r] * dinv);
      if (li < 4) {
        float z = accp[rf][r] * dinv - xp[(((size_t)b * Nn + n) << 2) + li];
        avz[((size_t)b * Nn + n) * 1088 + 1024 + (h << 2) + li] = (__bf16)z;
      }
    }
  }
}

// ---------------- finalize: attn = em * dinv (streaming) ----------------
__launch_bounds__(256)
__global__ void attn_fin(const __bf16* __restrict__ em_g, const float* __restrict__ dinv_g,
                         float* __restrict__ attn_out) {
  for (size_t i8 = blockIdx.x * 256ul + threadIdx.x; i8 < 16777216ul; i8 += 524288ul) {
    bf16x8 v = ((const bf16x8*)em_g)[i8];
    float dv = dinv_g[i8 >> 8];
    float4 o0, o1;
    o0.x = (float)v[0] * dv; o0.y = (float)v[1] * dv; o0.z = (float)v[2] * dv; o0.w = (float)v[3] * dv;
    o1.x = (float)v[4] * dv; o1.y = (float)v[5] * dv; o1.z = (float)v[6] * dv; o1.w = (float)v[7] * dv;
    ((float4*)attn_out)[i8 * 2]     = o0;
    ((float4*)attn_out)[i8 * 2 + 1] = o1;
  }
}

// ---------------- host ----------------
extern "C" void kernel_launch(void* const* d_in, const int* in_sizes, int n_in,
                              void* d_out, int out_size, void* d_ws, size_t ws_size,
                              hipStream_t stream) {
  (void)in_sizes; (void)n_in; (void)out_size; (void)ws_size;
  const float* x       = (const float*)d_in[0];
  const float* xp      = (const float*)d_in[1];
  const float* y       = (const float*)d_in[2];
  const float* yp      = (const float*)d_in[3];
  const float* mask    = (const float*)d_in[4];
  const float* p_w1    = (const float*)d_in[5];
  const float* p_b1    = (const float*)d_in[6];
  const float* p_w2    = (const float*)d_in[7];
  const float* p_b2    = (const float*)d_in[8];
  const float* q_ln_g  = (const float*)d_in[9];
  const float* q_ln_b  = (const float*)d_in[10];
  const float* q_m1_w1 = (const float*)d_in[11];
  const float* q_m1_b1 = (const float*)d_in[12];
  const float* q_m1_w2 = (const float*)d_in[13];
  const float* q_m1_b2 = (const float*)d_in[14];
  const float* q_m2_w1 = (const float*)d_in[15];
  const float* q_m2_b1 = (const float*)d_in[16];
  const float* q_m2_w2 = (const float*)d_in[17];
  const float* q_m2_b2 = (const float*)d_in[18];
  const float* k_ln_g  = (const float*)d_in[19];
  const float* k_ln_b  = (const float*)d_in[20];
  const float* k_m1_w1 = (const float*)d_in[21];
  const float* k_m1_b1 = (const float*)d_in[22];
  const float* k_m1_w2 = (const float*)d_in[23];
  const float* k_m1_b2 = (const float*)d_in[24];
  const float* v_ln_g  = (const float*)d_in[25];
  const float* v_ln_b  = (const float*)d_in[26];
  const float* v_w     = (const float*)d_in[27];
  const float* v_b     = (const float*)d_in[28];
  const float* proj1_w = (const float*)d_in[29];
  const float* proj1_b = (const float*)d_in[30];
  const float* proj2_w = (const float*)d_in[31];
  const float* proj2_b = (const float*)d_in[32];

  char* ws = (char*)d_ws;
  __bf16* xn   = (__bf16*)(ws + OFF_XN);
  __bf16* ynk  = (__bf16*)(ws + OFF_YNK);
  __bf16* ynv  = (__bf16*)(ws + OFF_YNV);
  __bf16* hbuf = (__bf16*)(ws + OFF_H);
  __bf16* x1   = (__bf16*)(ws + OFF_X1);
  __bf16* x2   = (__bf16*)(ws + OFF_X2);
  __bf16* y1   = (__bf16*)(ws + OFF_Y1);
  __bf16* q_ws = (__bf16*)(ws + OFF_QWS);
  __bf16* k_ws = (__bf16*)(ws + OFF_KWS);
  __bf16* vT_ws= (__bf16*)(ws + OFF_VWS);
  float*  dinv = (float*)(ws + OFF_DNV);
  __bf16* ypT  = (__bf16*)(ws + OFF_YPT);
  __bf16* avz  = (__bf16*)(ws + OFF_AVZ);
  __bf16* w11  = (__bf16*)(ws + OFF_W11);
  __bf16* w12  = (__bf16*)(ws + OFF_W12);
  __bf16* w21  = (__bf16*)(ws + OFF_W21);
  __bf16* w22  = (__bf16*)(ws + OFF_W22);
  __bf16* wk1  = (__bf16*)(ws + OFF_WK1);
  __bf16* wk2  = (__bf16*)(ws + OFF_WK2);
  __bf16* wv   = (__bf16*)(ws + OFF_WV);
  __bf16* wp   = (__bf16*)(ws + OFF_WP);
  __bf16* em   = (__bf16*)(ws + OFF_EM);

  float* out0     = (float*)d_out;
  float* attn_out = out0 + (size_t)4194304;
  float* xp_out   = out0 + (size_t)138412032;

  // weight conversions
  cvt_bf16<<<2048, 256, 0, stream>>>(q_m1_w1, w11, 524288);
  cvt_bf16<<<2048, 256, 0, stream>>>(q_m1_w2, w12, 524288);
  cvt_bf16<<<2048, 256, 0, stream>>>(q_m2_w1, w21, 524288);
  cvt_bf16<<<2048, 256, 0, stream>>>(q_m2_w2, w22, 524288);
  cvt_bf16<<<2048, 256, 0, stream>>>(k_m1_w1, wk1, 524288);
  cvt_bf16<<<2048, 256, 0, stream>>>(k_m1_w2, wk2, 524288);
  cvt_bf16<<<1024, 256, 0, stream>>>(v_w, wv, 262144);
  cvt_proj<<<1024, 256, 0, stream>>>(proj1_w, proj2_w, wp);
  yp_tr<<<64, 256, 0, stream>>>(yp, ypT);

  // layernorms
  ln_kernel<<<4096, 256, 0, stream>>>(x, q_ln_g, q_ln_b, xn);
  ln_kernel<<<4096, 256, 0, stream>>>(y, k_ln_g, k_ln_b, ynk);
  ln_kernel<<<4096, 256, 0, stream>>>(y, v_ln_g, v_ln_b, ynv);

  // encoders
  gemm_nt<1><<<512, 256, 0, stream>>>(xn, 1024, w11, 1024, q_m1_b1, nullptr, hbuf, 4096, 2048, 1024);
  gemm_nt<0><<<256, 256, 0, stream>>>(hbuf, 2048, w12, 2048, q_m1_b2, nullptr, x1, 4096, 1024, 2048);
  gemm_nt<1><<<512, 256, 0, stream>>>(xn, 1024, w21, 1024, q_m2_b1, nullptr, hbuf, 4096, 2048, 1024);
  gemm_nt<0><<<256, 256, 0, stream>>>(hbuf, 2048, w22, 2048, q_m2_b2, nullptr, x2, 4096, 1024, 2048);
  gemm_nt<1><<<512, 256, 0, stream>>>(ynk, 1024, wk1, 1024, k_m1_b1, nullptr, hbuf, 4096, 2048, 1024);
  gemm_nt<0><<<256, 256, 0, stream>>>(hbuf, 2048, wk2, 2048, k_m1_b2, nullptr, y1, 4096, 1024, 2048);
  gemm_nt<2><<<256, 256, 0, stream>>>(ynv, 1024, wv, 1024, v_b, nullptr, vT_ws, 4096, 1024, 1024);

  build_q<<<4096, 256, 0, stream>>>(x1, x2, xp, p_w1, p_b1, p_w2, p_b2, q_ws);
  build_k<<<4096, 256, 0, stream>>>(y1, yp, p_w1, p_w2, k_ws);

  // attention (single fused pass + streaming finalize)
  attn_fused<<<256, 512, 0, stream>>>(q_ws, k_ws, vT_ws, ypT, mask, xp, em, dinv, avz);
  attn_fin<<<2048, 256, 0, stream>>>(em, dinv, attn_out);

  // fused output projection: out0 = avz @ [proj1_w | proj2_w]^T + proj1_b + proj2_b
  gemm_nt<3><<<256, 256, 0, stream>>>(avz, 1088, wp, 1088, proj1_b, proj2_b, out0, 4096, 1024, 1088);

  // third output: xp passthrough
  hipMemcpyAsync(xp_out, d_in[1], 65536, hipMemcpyDeviceToDevice, stream);
}

// Round 3
// 789.654 us; speedup vs baseline: 1.1328x; 1.0797x over previous
//
#include <hip/hip_runtime.h>
#include <math.h>
#include <stdint.h>

#define DEV static __device__ __forceinline__

typedef __bf16 bf16x8 __attribute__((ext_vector_type(8)));
typedef __bf16 bf16x4v __attribute__((ext_vector_type(4)));
typedef float f32x4 __attribute__((ext_vector_type(4)));

// problem dims
constexpr int Nn = 2048, Ll = 2048, Ee = 1024, Hh = 16;
constexpr float SCALE = 0.0625f;   // (4C)^-0.5 = 1/16

// ---------------- workspace layout (bytes) ----------------
constexpr size_t OFF_XN   = 0;                          // [4096][1024] bf16
constexpr size_t OFF_YNK  = OFF_XN   + 8388608;
constexpr size_t OFF_YNV  = OFF_YNK  + 8388608;
constexpr size_t OFF_H12  = OFF_YNV  + 8388608;         // [4096][4096] bf16 (merged h1|h2)
constexpr size_t OFF_H3   = OFF_H12  + 33554432;        // [4096][2048] bf16
constexpr size_t OFF_X1   = OFF_H3   + 16777216;
constexpr size_t OFF_X2   = OFF_X1   + 8388608;
constexpr size_t OFF_Y1   = OFF_X2   + 8388608;
constexpr size_t OFF_QWS  = OFF_Y1   + 8388608;         // [B][H][N][256] bf16, pre-swizzled
constexpr size_t OFF_KWS  = OFF_QWS  + 33554432;        // [B][H][L][256] bf16, pre-swizzled
constexpr size_t OFF_VWS  = OFF_KWS  + 33554432;        // vT: [B*H][64][2048] bf16
constexpr size_t OFF_DNV  = OFF_VWS  + 8388608;         // f32 [B*H*N] dinv
constexpr size_t OFF_YPT  = OFF_DNV  + 262144;          // ypT [B][4][2048] bf16
constexpr size_t OFF_AVZ  = OFF_YPT  + 262144;          // [4096][1088] bf16 : [attn_v | z]
constexpr size_t OFF_W1122= OFF_AVZ  + 8912896;         // [4096][1024] bf16 (w11 ; w21)
constexpr size_t OFF_W12  = OFF_W1122+ 8388608;
constexpr size_t OFF_W22  = OFF_W12  + 4194304;
constexpr size_t OFF_WK1  = OFF_W22  + 4194304;
constexpr size_t OFF_WK2  = OFF_WK1  + 4194304;
constexpr size_t OFF_WV   = OFF_WK2  + 4194304;
constexpr size_t OFF_WP   = OFF_WV   + 2097152;         // [1024][1088] bf16 fused proj
constexpr size_t OFF_EM   = OFF_WP   + 2228224;         // em bf16 [B*H][2048][2048] = 268MB

DEV void gl2l(const void* g, void* l) {
  __builtin_amdgcn_global_load_lds((const __attribute__((address_space(1))) void*)g,
                                   (__attribute__((address_space(3))) void*)l, 16, 0, 0);
}

// ---------------- merged weight conversion (7 segments, one launch) ----------------
__launch_bounds__(256)
__global__ void cvt_all(const float* __restrict__ s0, const float* __restrict__ s1,
                        const float* __restrict__ s2, const float* __restrict__ s3,
                        const float* __restrict__ s4, const float* __restrict__ s5,
                        const float* __restrict__ s6,
                        __bf16* __restrict__ d0, __bf16* __restrict__ d1,
                        __bf16* __restrict__ d2, __bf16* __restrict__ d3,
                        __bf16* __restrict__ d4, __bf16* __restrict__ d5,
                        __bf16* __restrict__ d6) {
  int i = blockIdx.x * 256 + threadIdx.x;          // float4 units
  int seg = i >> 19, r = i & 524287;
  const float* s; __bf16* d;
  if      (seg == 0) { s = s0; d = d0; }
  else if (seg == 1) { s = s1; d = d1; }
  else if (seg == 2) { s = s2; d = d2; }
  else if (seg == 3) { s = s3; d = d3; }
  else if (seg == 4) { s = s4; d = d4; }
  else if (seg == 5) { s = s5; d = d5; }
  else               { if (r >= 262144) return; s = s6; d = d6; }
  float4 v = ((const float4*)s)[r];
  bf16x4v o; o[0]=(__bf16)v.x; o[1]=(__bf16)v.y; o[2]=(__bf16)v.z; o[3]=(__bf16)v.w;
  ((bf16x4v*)d)[r] = o;
}

__launch_bounds__(256)
__global__ void cvt_proj(const float* __restrict__ w1, const float* __restrict__ w2,
                         __bf16* __restrict__ d) {
  for (size_t i = blockIdx.x * 256ul + threadIdx.x; i < 1024ul * 1088ul; i += 262144ul) {
    size_t row = i / 1088, col = i - row * 1088;
    float v = (col < 1024) ? w1[row * 1024 + col] : w2[(row << 6) + (col - 1024)];
    d[i] = (__bf16)v;
  }
}

// yp [B][L][4] f32 -> ypT [B][4][L] bf16
__launch_bounds__(256)
__global__ void yp_tr(const float* __restrict__ yp, __bf16* __restrict__ ypT) {
  int i = blockIdx.x * 256 + threadIdx.x;   // 16384
  int b = i >> 13, d = (i >> 11) & 3, l = i & 2047;
  ypT[i] = (__bf16)yp[(((size_t)b << 11) + l) * 4 + d];
}

// ---------------- LayerNorm (one block per token) ----------------
__launch_bounds__(256)
__global__ void ln_kernel(const float* __restrict__ x, const float* __restrict__ gam,
                          const float* __restrict__ bet, __bf16* __restrict__ out) {
  const int t = blockIdx.x, tid = threadIdx.x;
  const float4 v = ((const float4*)(x + (size_t)t * Ee))[tid];
  float s = v.x + v.y + v.z + v.w;
  float q = v.x*v.x + v.y*v.y + v.z*v.z + v.w*v.w;
  #pragma unroll
  for (int o = 32; o > 0; o >>= 1) { s += __shfl_down(s, o); q += __shfl_down(q, o); }
  __shared__ float ls[4], lq[4];
  if ((tid & 63) == 0) { ls[tid >> 6] = s; lq[tid >> 6] = q; }
  __syncthreads();
  s = ls[0] + ls[1] + ls[2] + ls[3];
  q = lq[0] + lq[1] + lq[2] + lq[3];
  const float mu = s * (1.f / Ee);
  const float rstd = rsqrtf(q * (1.f / Ee) - mu * mu + 1e-5f);
  const int e0 = tid << 2;
  bf16x4v o;
  o[0] = (__bf16)((v.x - mu) * rstd * gam[e0]   + bet[e0]);
  o[1] = (__bf16)((v.y - mu) * rstd * gam[e0+1] + bet[e0+1]);
  o[2] = (__bf16)((v.z - mu) * rstd * gam[e0+2] + bet[e0+2]);
  o[3] = (__bf16)((v.w - mu) * rstd * gam[e0+3] + bet[e0+3]);
  *(bf16x4v*)(out + (size_t)t * Ee + e0) = o;
}

// ---------------- NT GEMM, 2-phase double-buffered ----------------
// C[m,n] = sum_k A[m,k] * W[n,k] (+bias). 128xBN tile, BK=32, 4 waves (2x2).
// MODE: 0 = bf16+bias; 1 = bf16+bias+GELU; 2 = vT layout+bias; 3 = f32+bias1+bias2;
//       4 = bf16+GELU, split bias (bias1 for n<2048, bias2 for n>=2048)
template<int MODE, int BN>
__launch_bounds__(256)
__global__ void gemm_nt(const __bf16* __restrict__ A, int lda,
                        const __bf16* __restrict__ W, int ldw,
                        const float* __restrict__ bias1, const float* __restrict__ bias2,
                        void* __restrict__ out, int M, int N, int K) {
  constexpr int NJ = BN / 32;
  __shared__ __align__(16) __bf16 As[2][128 * 32];
  __shared__ __align__(16) __bf16 Bs[2][BN * 32];
  const int tid = threadIdx.x;
  const int w = tid >> 6, lane = tid & 63, g = lane >> 4, li = lane & 15;
  const int ntn = N / BN;
  const int bt = blockIdx.x / ntn;
  const int m0 = bt << 7, n0 = (blockIdx.x - bt * ntn) * BN;
  const int wm = (w >> 1) << 6, wn = (w & 1) * (BN / 2);
  f32x4 acc[4][NJ];
  #pragma unroll
  for (int i = 0; i < 4; i++)
    #pragma unroll
    for (int j = 0; j < NJ; j++) acc[i][j] = (f32x4)0.f;

  auto stage = [&](int buf, int kt) {
    const int col0 = kt << 5;
    #pragma unroll
    for (int j = 0; j < 2; j++) {
      int c = (j << 8) + tid;
      int row = c >> 2, sl = c & 3;
      int col = col0 + ((sl ^ (row & 3)) << 3);
      gl2l(A + (size_t)(m0 + row) * lda + col, As[buf] + ((c - lane) << 3));
    }
    #pragma unroll
    for (int j = 0; j < BN / 64; j++) {
      int c = (j << 8) + tid;
      int row = c >> 2, sl = c & 3;
      int col = col0 + ((sl ^ (row & 3)) << 3);
      gl2l(W + (size_t)(n0 + row) * ldw + col, Bs[buf] + ((c - lane) << 3));
    }
  };

  const int NT = K >> 5;
  stage(0, 0);
  __syncthreads();
  for (int kt = 0; kt < NT; kt++) {
    const int cur = kt & 1;
    if (kt + 1 < NT) stage(cur ^ 1, kt + 1);   // prefetch next tile (flies under compute)
    bf16x8 af[4], bw[NJ];
    #pragma unroll
    for (int i = 0; i < 4; i++) {
      int ra = wm + (i << 4) + li;
      af[i] = *(const bf16x8*)(As[cur] + ra * 32 + ((g ^ (ra & 3)) << 3));
    }
    #pragma unroll
    for (int j = 0; j < NJ; j++) {
      int rb = wn + (j << 4) + li;
      bw[j] = *(const bf16x8*)(Bs[cur] + rb * 32 + ((g ^ (rb & 3)) << 3));
    }
    #pragma unroll
    for (int i = 0; i < 4; i++)
      #pragma unroll
      for (int j = 0; j < NJ; j++)
        acc[i][j] = __builtin_amdgcn_mfma_f32_16x16x32_bf16(af[i], bw[j], acc[i][j], 0, 0, 0);
    __syncthreads();   // drains vmcnt(0): prefetched tile landed; all waves done reading cur
  }

  #pragma unroll
  for (int j = 0; j < NJ; j++) {
    int n = n0 + wn + (j << 4) + li;
    float bias;
    if (MODE == 4) bias = (n < 2048) ? bias1[n] : bias2[n - 2048];
    else { bias = bias1[n]; if (MODE == 3) bias += bias2[n]; }
    #pragma unroll
    for (int i = 0; i < 4; i++) {
      #pragma unroll
      for (int r = 0; r < 4; r++) {
        int m = m0 + wm + (i << 4) + (g << 2) + r;
        float v = acc[i][j][r] + bias;
        if (MODE == 1 || MODE == 4) v = 0.5f * v * (1.f + erff(v * 0.70710678118654752f));
        if (MODE == 3) {
          ((float*)out)[(size_t)m * N + n] = v;
        } else if (MODE == 2) {   // vT: [B*H][64][2048]
          int bb = m >> 11, l = m & 2047, hh = n >> 6, cc = n & 63;
          ((__bf16*)out)[(((size_t)(bb * Hh + hh) * 64 + cc) << 11) + l] = (__bf16)v;
        } else {
          ((__bf16*)out)[(size_t)m * N + n] = (__bf16)v;
        }
      }
    }
  }
}

// ---------------- build q / k (vectorized: 4x 16B stores per thread) ----------------
// q_ws/k_ws rows are 256 bf16 = 32 16B-chunks, chunk-index XOR'd with (row&7).
__launch_bounds__(256)
__global__ void build_q(const __bf16* __restrict__ x1, const __bf16* __restrict__ x2,
                        const float* __restrict__ xp,
                        const float* __restrict__ pw1, const float* __restrict__ pb1,
                        const float* __restrict__ pw2, const float* __restrict__ pb2,
                        __bf16* __restrict__ q_ws) {
  const int t = (blockIdx.x << 1) + (threadIdx.x >> 7);   // 2 tokens/block
  const int tl = threadIdx.x & 127;
  const int b = t >> 11, n = t & 2047;
  const int hh = tl >> 3, ch = tl & 7;
  const int e0 = (hh << 6) + (ch << 3);
  const float p0 = xp[(size_t)t*4], p1 = xp[(size_t)t*4+1], p2 = xp[(size_t)t*4+2], p3 = xp[(size_t)t*4+3];
  bf16x8 v1 = *(const bf16x8*)(x1 + (size_t)t * Ee + e0);
  bf16x8 v2 = *(const bf16x8*)(x2 + (size_t)t * Ee + e0);
  bf16x8 o0, o1, o2, o3;
  #pragma unroll
  for (int sub = 0; sub < 8; sub++) {
    int e = e0 + sub;
    float a1 = pw1[e*4]*p0 + pw1[e*4+1]*p1 + pw1[e*4+2]*p2 + pw1[e*4+3]*p3 + pb1[e];
    float a2 = pw2[e*4]*p0 + pw2[e*4+1]*p1 + pw2[e*4+2]*p2 + pw2[e*4+3]*p3 + pb2[e];
    float s1, c1, s2, c2;
    __sincosf(a1, &s1, &c1); __sincosf(a2, &s2, &c2);
    float xv1 = (float)v1[sub], xv2 = (float)v2[sub];
    o0[sub] = (__bf16)(xv1 * c1); o1[sub] = (__bf16)(xv1 * s1);
    o2[sub] = (__bf16)(xv2 * c2); o3[sub] = (__bf16)(xv2 * s2);
  }
  const int k = n & 7, bc = ch ^ k;
  __bf16* base = q_ws + ((((size_t)b * Hh + hh) * Nn + n) << 8);
  *(bf16x8*)(base + ((bc     ) << 3)) = o0;
  *(bf16x8*)(base + ((bc +  8) << 3)) = o1;
  *(bf16x8*)(base + ((bc + 16) << 3)) = o2;
  *(bf16x8*)(base + ((bc + 24) << 3)) = o3;
}

__launch_bounds__(256)
__global__ void build_k(const __bf16* __restrict__ y1, const float* __restrict__ yp,
                        const float* __restrict__ pw1, const float* __restrict__ pw2,
                        __bf16* __restrict__ k_ws) {
  const int t = (blockIdx.x << 1) + (threadIdx.x >> 7);
  const int tl = threadIdx.x & 127;
  const int b = t >> 11, l = t & 2047;
  const int hh = tl >> 3, ch = tl & 7;
  const int e0 = (hh << 6) + (ch << 3);
  const float p0 = yp[(size_t)t*4], p1 = yp[(size_t)t*4+1], p2 = yp[(size_t)t*4+2], p3 = yp[(size_t)t*4+3];
  bf16x8 v1 = *(const bf16x8*)(y1 + (size_t)t * Ee + e0);
  bf16x8 o0, o1, o2, o3;
  #pragma unroll
  for (int sub = 0; sub < 8; sub++) {
    int e = e0 + sub;
    float a1 = pw1[e*4]*p0 + pw1[e*4+1]*p1 + pw1[e*4+2]*p2 + pw1[e*4+3]*p3;  // no bias
    float a2 = pw2[e*4]*p0 + pw2[e*4+1]*p1 + pw2[e*4+2]*p2 + pw2[e*4+3]*p3;
    float s1, c1, s2, c2;
    __sincosf(a1, &s1, &c1); __sincosf(a2, &s2, &c2);
    float yv = (float)v1[sub];
    o0[sub] = (__bf16)(yv * c1); o1[sub] = (__bf16)(yv * s1);
    o2[sub] = (__bf16)c2;        o3[sub] = (__bf16)s2;      // raw position code
  }
  const int k = l & 7, bc = ch ^ k;
  __bf16* base = k_ws + ((((size_t)b * Hh + hh) * Ll + l) << 8);
  *(bf16x8*)(base + ((bc     ) << 3)) = o0;
  *(bf16x8*)(base + ((bc +  8) << 3)) = o1;
  *(bf16x8*)(base + ((bc + 16) << 3)) = o2;
  *(bf16x8*)(base + ((bc + 24) << 3)) = o3;
}

// ---------------- fused flash attention (single QK^T pass, no max) ----------------
__launch_bounds__(512, 2)
__global__ void attn_fused(const __bf16* __restrict__ q_ws, const __bf16* __restrict__ k_ws,
                           const __bf16* __restrict__ vT_ws, const __bf16* __restrict__ ypT_g,
                           const float* __restrict__ mask, const float* __restrict__ xp,
                           __bf16* __restrict__ em_g, float* __restrict__ dinv_g,
                           __bf16* __restrict__ avz) {
  __shared__ __align__(16) __bf16 kq[2][32 * 256];   // 32 KB, pre-swizzled rows
  __shared__ __align__(16) __bf16 vt[2][64 * 40];    // padded rows (80B)
  __shared__ __align__(16) __bf16 pT[256 * 40];      // padded rows (80B)
  __shared__ __align__(16) __bf16 ypl[2][16 * 40];
  const int tid = threadIdx.x, w = tid >> 6, lane = tid & 63, g = lane >> 4, li = lane & 15;
  const int bh = blockIdx.x & 31, nt = blockIdx.x >> 5;
  const int b = bh >> 4, h = bh & 15;
  const int n0 = nt << 8;
  const __bf16* qb = q_ws + (((size_t)bh * Nn + n0) << 8);
  const __bf16* kb = k_ws + (((size_t)bh * Ll) << 8);
  const __bf16* vb = vT_ws + ((size_t)bh << 17);
  const __bf16* yb = ypT_g + ((size_t)b << 13);

  // Q fragments direct from (pre-swizzled) global
  bf16x8 aq[2][8];
  #pragma unroll
  for (int rf = 0; rf < 2; rf++) {
    const int nloc = (w << 5) + (rf << 4) + li;
    #pragma unroll
    for (int s = 0; s < 8; s++) {
      int cc = (s << 2) + g;
      aq[rf][s] = *(const bf16x8*)(qb + ((size_t)nloc << 8) + ((cc ^ (nloc & 7)) << 3));
    }
  }
  // zero ypl rows 4..15 (both buffers)
  for (int i = tid; i < 960; i += 512) {
    int buf = i / 480, idx = i - buf * 480;
    ypl[buf][160 + idx] = (__bf16)0.f;
  }
  // prologue: stage tile 0
  {
    const int vc = tid >> 3, vl = (tid & 7) << 2;
    bf16x4v vreg = *(const bf16x4v*)(vb + ((size_t)vc << 11) + vl);
    bf16x4v ypreg;
    if (tid < 32) ypreg = *(const bf16x4v*)(yb + ((size_t)(tid >> 3) << 11) + ((tid & 7) << 2));
    #pragma unroll
    for (int j = 0; j < 2; j++) {
      int c = (j << 9) + tid;
      int row = c >> 5, ch = c & 31;
      gl2l(kb + (size_t)row * 256 + (ch << 3), kq[0] + ((c - lane) << 3));
    }
    *(bf16x4v*)(vt[0] + vc * 40 + vl) = vreg;
    if (tid < 32) *(bf16x4v*)(ypl[0] + (tid >> 3) * 40 + ((tid & 7) << 2)) = ypreg;
  }
  __syncthreads();

  float se[2][4], te[2][4];
  f32x4 accv[2][4], accp[2];
  #pragma unroll
  for (int rf = 0; rf < 2; rf++) {
    #pragma unroll
    for (int r = 0; r < 4; r++) { se[rf][r] = 0.f; te[rf][r] = 0.f; }
    #pragma unroll
    for (int cb = 0; cb < 4; cb++) accv[rf][cb] = (f32x4)0.f;
    accp[rf] = (f32x4)0.f;
  }

  for (int t = 0; t < 64; ++t) {
    const int l0 = t << 5, cur = t & 1, nxt = cur ^ 1;
    const bool more = (t < 63);
    bf16x4v vreg, ypreg;
    if (more) {
      const int l1 = l0 + 32;
      vreg = *(const bf16x4v*)(vb + ((size_t)(tid >> 3) << 11) + l1 + ((tid & 7) << 2));
      if (tid < 32) ypreg = *(const bf16x4v*)(yb + ((size_t)(tid >> 3) << 11) + l1 + ((tid & 7) << 2));
      #pragma unroll
      for (int j = 0; j < 2; j++) {
        int c = (j << 9) + tid;
        int row = c >> 5, ch = c & 31;
        gl2l(kb + (size_t)(l1 + row) * 256 + (ch << 3), kq[nxt] + ((c - lane) << 3));
      }
    }
    // QK^T: K-fragment reads hoisted & shared across both row-fragments (16 b128 reads)
    f32x4 Cs[2][2];
    Cs[0][0] = (f32x4)0.f; Cs[0][1] = (f32x4)0.f; Cs[1][0] = (f32x4)0.f; Cs[1][1] = (f32x4)0.f;
    #pragma unroll
    for (int lb = 0; lb < 2; lb++) {
      const int kr = (lb << 4) + li;
      #pragma unroll
      for (int s = 0; s < 8; s++) {
        int cc = (s << 2) + g;
        bf16x8 bk = *(const bf16x8*)(kq[cur] + kr * 256 + ((cc ^ (kr & 7)) << 3));
        Cs[0][lb] = __builtin_amdgcn_mfma_f32_16x16x32_bf16(aq[0][s], bk, Cs[0][lb], 0, 0, 0);
        Cs[1][lb] = __builtin_amdgcn_mfma_f32_16x16x32_bf16(aq[1][s], bk, Cs[1][lb], 0, 0, 0);
      }
    }
    // exp + mask + sums + pT write
    #pragma unroll
    for (int rf = 0; rf < 2; rf++) {
      const int rbase = n0 + (w << 5) + (rf << 4) + (g << 2);
      #pragma unroll
      for (int lb = 0; lb < 2; lb++) {
        #pragma unroll
        for (int r = 0; r < 4; r++) {
          float e = __expf(Cs[rf][lb][r] * SCALE);
          float mkv = mask[(size_t)(rbase + r) * Ll + l0 + (lb << 4) + li];
          float em = e * mkv;
          se[rf][r] += e; te[rf][r] += em;
          pT[((w << 5) + (rf << 4) + (g << 2) + r) * 40 + (lb << 4) + li] = (__bf16)em;
        }
      }
    }
    asm volatile("s_waitcnt lgkmcnt(0)" ::: "memory");
    __builtin_amdgcn_sched_barrier(0);
    // em global store (vectorized from pT; wave-private rows)
    #pragma unroll
    for (int j = 0; j < 2; j++) {
      int q = (j << 6) + lane;
      int row = q >> 2, ch = q & 3;
      bf16x8 pv = *(const bf16x8*)(pT + ((w << 5) + row) * 40 + (ch << 3));
      *(bf16x8*)(em_g + ((size_t)bh << 22) + ((size_t)(n0 + (w << 5) + row) << 11) + l0 + (ch << 3)) = pv;
    }
    // PV + attn@yp
    bf16x8 vv[4];
    #pragma unroll
    for (int cb = 0; cb < 4; cb++)
      vv[cb] = *(const bf16x8*)(vt[cur] + ((cb << 4) + li) * 40 + (g << 3));
    bf16x8 yy = *(const bf16x8*)(ypl[cur] + li * 40 + (g << 3));
    #pragma unroll
    for (int rf = 0; rf < 2; rf++) {
      bf16x8 pa = *(const bf16x8*)(pT + ((w << 5) + (rf << 4) + li) * 40 + (g << 3));
      #pragma unroll
      for (int cb = 0; cb < 4; cb++)
        accv[rf][cb] = __builtin_amdgcn_mfma_f32_16x16x32_bf16(pa, vv[cb], accv[rf][cb], 0, 0, 0);
      accp[rf] = __builtin_amdgcn_mfma_f32_16x16x32_bf16(pa, yy, accp[rf], 0, 0, 0);
    }
    // write staged v/yp for next tile
    if (more) {
      *(bf16x4v*)(vt[nxt] + (tid >> 3) * 40 + ((tid & 7) << 2)) = vreg;
      if (tid < 32) *(bf16x4v*)(ypl[nxt] + (tid >> 3) * 40 + ((tid & 7) << 2)) = ypreg;
    }
    __syncthreads();
  }

  // epilogue: reduce sums, write dinv + avz
  #pragma unroll
  for (int rf = 0; rf < 2; rf++) {
    #pragma unroll
    for (int r = 0; r < 4; r++) {
      float s = se[rf][r], tt = te[rf][r];
      #pragma unroll
      for (int o = 1; o < 16; o <<= 1) { s += __shfl_xor(s, o); tt += __shfl_xor(tt, o); }
      float dinv = 1.f / (tt + 1e-8f * s);
      const int n = n0 + (w << 5) + (rf << 4) + (g << 2) + r;
      if (li == 0) dinv_g[((size_t)bh << 11) + n] = dinv;
      #pragma unroll
      for (int cb = 0; cb < 4; cb++)
        avz[((size_t)b * Nn + n) * 1088 + (h << 6) + (cb << 4) + li] = (__bf16)(accv[rf][cb][r] * dinv);
      if (li < 4) {
        float z = accp[rf][r] * dinv - xp[(((size_t)b * Nn + n) << 2) + li];
        avz[((size_t)b * Nn + n) * 1088 + 1024 + (h << 2) + li] = (__bf16)z;
      }
    }
  }
}

// ---------------- finalize: attn = em * dinv (streaming) ----------------
__launch_bounds__(256)
__global__ void attn_fin(const __bf16* __restrict__ em_g, const float* __restrict__ dinv_g,
                         float* __restrict__ attn_out) {
  for (size_t i8 = blockIdx.x * 256ul + threadIdx.x; i8 < 16777216ul; i8 += 524288ul) {
    bf16x8 v = ((const bf16x8*)em_g)[i8];
    float dv = dinv_g[i8 >> 8];
    float4 o0, o1;
    o0.x = (float)v[0] * dv; o0.y = (float)v[1] * dv; o0.z = (float)v[2] * dv; o0.w = (float)v[3] * dv;
    o1.x = (float)v[4] * dv; o1.y = (float)v[5] * dv; o1.z = (float)v[6] * dv; o1.w = (float)v[7] * dv;
    ((float4*)attn_out)[i8 * 2]     = o0;
    ((float4*)attn_out)[i8 * 2 + 1] = o1;
  }
}

// ---------------- host ----------------
extern "C" void kernel_launch(void* const* d_in, const int* in_sizes, int n_in,
                              void* d_out, int out_size, void* d_ws, size_t ws_size,
                              hipStream_t stream) {
  (void)in_sizes; (void)n_in; (void)out_size; (void)ws_size;
  const float* x       = (const float*)d_in[0];
  const float* xp      = (const float*)d_in[1];
  const float* y       = (const float*)d_in[2];
  const float* yp      = (const float*)d_in[3];
  const float* mask    = (const float*)d_in[4];
  const float* p_w1    = (const float*)d_in[5];
  const float* p_b1    = (const float*)d_in[6];
  const float* p_w2    = (const float*)d_in[7];
  const float* p_b2    = (const float*)d_in[8];
  const float* q_ln_g  = (const float*)d_in[9];
  const float* q_ln_b  = (const float*)d_in[10];
  const float* q_m1_w1 = (const float*)d_in[11];
  const float* q_m1_b1 = (const float*)d_in[12];
  const float* q_m1_w2 = (const float*)d_in[13];
  const float* q_m1_b2 = (const float*)d_in[14];
  const float* q_m2_w1 = (const float*)d_in[15];
  const float* q_m2_b1 = (const float*)d_in[16];
  const float* q_m2_w2 = (const float*)d_in[17];
  const float* q_m2_b2 = (const float*)d_in[18];
  const float* k_ln_g  = (const float*)d_in[19];
  const float* k_ln_b  = (const float*)d_in[20];
  const float* k_m1_w1 = (const float*)d_in[21];
  const float* k_m1_b1 = (const float*)d_in[22];
  const float* k_m1_w2 = (const float*)d_in[23];
  const float* k_m1_b2 = (const float*)d_in[24];
  const float* v_ln_g  = (const float*)d_in[25];
  const float* v_ln_b  = (const float*)d_in[26];
  const float* v_w     = (const float*)d_in[27];
  const float* v_b     = (const float*)d_in[28];
  const float* proj1_w = (const float*)d_in[29];
  const float* proj1_b = (const float*)d_in[30];
  const float* proj2_w = (const float*)d_in[31];
  const float* proj2_b = (const float*)d_in[32];

  char* ws = (char*)d_ws;
  __bf16* xn    = (__bf16*)(ws + OFF_XN);
  __bf16* ynk   = (__bf16*)(ws + OFF_YNK);
  __bf16* ynv   = (__bf16*)(ws + OFF_YNV);
  __bf16* h12   = (__bf16*)(ws + OFF_H12);
  __bf16* h3    = (__bf16*)(ws + OFF_H3);
  __bf16* x1    = (__bf16*)(ws + OFF_X1);
  __bf16* x2    = (__bf16*)(ws + OFF_X2);
  __bf16* y1    = (__bf16*)(ws + OFF_Y1);
  __bf16* q_ws  = (__bf16*)(ws + OFF_QWS);
  __bf16* k_ws  = (__bf16*)(ws + OFF_KWS);
  __bf16* vT_ws = (__bf16*)(ws + OFF_VWS);
  float*  dinv  = (float*)(ws + OFF_DNV);
  __bf16* ypT   = (__bf16*)(ws + OFF_YPT);
  __bf16* avz   = (__bf16*)(ws + OFF_AVZ);
  __bf16* w1122 = (__bf16*)(ws + OFF_W1122);
  __bf16* w12   = (__bf16*)(ws + OFF_W12);
  __bf16* w22   = (__bf16*)(ws + OFF_W22);
  __bf16* wk1   = (__bf16*)(ws + OFF_WK1);
  __bf16* wk2   = (__bf16*)(ws + OFF_WK2);
  __bf16* wv    = (__bf16*)(ws + OFF_WV);
  __bf16* wp    = (__bf16*)(ws + OFF_WP);
  __bf16* em    = (__bf16*)(ws + OFF_EM);

  float* out0     = (float*)d_out;
  float* attn_out = out0 + (size_t)4194304;
  float* xp_out   = out0 + (size_t)138412032;

  // weight conversions (one merged launch + proj + ypT)
  cvt_all<<<13312, 256, 0, stream>>>(q_m1_w1, q_m2_w1, q_m1_w2, q_m2_w2, k_m1_w1, k_m1_w2, v_w,
                                     w1122, w1122 + 2097152, w12, w22, wk1, wk2, wv);
  cvt_proj<<<1024, 256, 0, stream>>>(proj1_w, proj2_w, wp);
  yp_tr<<<64, 256, 0, stream>>>(yp, ypT);

  // layernorms
  ln_kernel<<<4096, 256, 0, stream>>>(x, q_ln_g, q_ln_b, xn);
  ln_kernel<<<4096, 256, 0, stream>>>(y, k_ln_g, k_ln_b, ynk);
  ln_kernel<<<4096, 256, 0, stream>>>(y, v_ln_g, v_ln_b, ynv);

  // encoders
  gemm_nt<4,128><<<1024, 256, 0, stream>>>(xn, 1024, w1122, 1024, q_m1_b1, q_m2_b1, h12, 4096, 4096, 1024);
  gemm_nt<0, 64><<< 512, 256, 0, stream>>>(h12,        4096, w12, 2048, q_m1_b2, nullptr, x1, 4096, 1024, 2048);
  gemm_nt<0, 64><<< 512, 256, 0, stream>>>(h12 + 2048, 4096, w22, 2048, q_m2_b2, nullptr, x2, 4096, 1024, 2048);
  gemm_nt<1,128><<< 512, 256, 0, stream>>>(ynk, 1024, wk1, 1024, k_m1_b1, nullptr, h3, 4096, 2048, 1024);
  gemm_nt<0, 64><<< 512, 256, 0, stream>>>(h3, 2048, wk2, 2048, k_m1_b2, nullptr, y1, 4096, 1024, 2048);
  gemm_nt<2, 64><<< 512, 256, 0, stream>>>(ynv, 1024, wv, 1024, v_b, nullptr, vT_ws, 4096, 1024, 1024);

  build_q<<<2048, 256, 0, stream>>>(x1, x2, xp, p_w1, p_b1, p_w2, p_b2, q_ws);
  build_k<<<2048, 256, 0, stream>>>(y1, yp, p_w1, p_w2, k_ws);

  // attention (single fused pass + streaming finalize)
  attn_fused<<<256, 512, 0, stream>>>(q_ws, k_ws, vT_ws, ypT, mask, xp, em, dinv, avz);
  attn_fin<<<2048, 256, 0, stream>>>(em, dinv, attn_out);

  // fused output projection: out0 = avz @ [proj1_w | proj2_w]^T + proj1_b + proj2_b
  gemm_nt<3, 64><<< 512, 256, 0, stream>>>(avz, 1088, wp, 1088, proj1_b, proj2_b, out0, 4096, 1024, 1088);

  // third output: xp passthrough
  hipMemcpyAsync(xp_out, d_in[1], 65536, hipMemcpyDeviceToDevice, stream);
}